// Round 8
// baseline (91.908 us; speedup 1.0000x reference)
//
#include <hip/hip_runtime.h>

// Bit-exact replica of XLA:CPU's vectorized f32 exp AS COMPILED with
// fast-math contraction (== Eigen classic pexp_float with pmadd=FMA on AVX2).
// Non-FMA ops must stay un-contracted -> pragma contract(off) + explicit fmaf.
__device__ __forceinline__ float xla_expf(float xin) {
#pragma clang fp contract(off)
  float xc = fminf(xin, 88.3762626647950f);
  xc = fmaxf(xc, -88.3762626647949f);
  float m = floorf(fmaf(xc, 1.44269504088896341f, 0.5f));
  float r = fmaf(m, -0.693359375f, xc);
  r = fmaf(m, 2.12194440e-4f, r);
  float r2 = r * r;
  float y = 1.9875691500E-4f;            // p0
  y = fmaf(y, r, 1.3981999507E-3f);      // p1
  y = fmaf(y, r, 8.3334519073E-3f);      // p2
  y = fmaf(y, r, 4.1665795894E-2f);      // p3
  y = fmaf(y, r, 1.6666665459E-1f);      // p4
  y = fmaf(y, r, 5.0000001201E-1f);      // p5
  y = fmaf(y, r2, r);
  y = y + 1.0f;
  int n = (int)m;
  float twon = __int_as_float((n + 127) << 23);
  float res = y * twon;
  return fmaxf(res, xin);                // final pmax vs UNCLAMPED input
}

__device__ __forceinline__ float xla_sigmoid(float f) {
#pragma clang fp contract(off)
  float e = xla_expf(-f);
  float denom = 1.0f + e;
  return 1.0f / denom;
}

// Segment = 64 consecutive bit-floats = 2 values. Lane j reads float j of the
// segment (coalesced 4B). ballot(pulse>0.5) -> lo32/hi32 bit-reversed are the
// two value words (wave-uniform). Per 8-segment iteration: 16 uniform values;
// lane L selects value L>>2 via a 15-cndmask static tree and computes ONE
// sigmoid (4x redundancy). Redistribute: lane j / segment k needs value
// 2k+(j>>5), held by lanes 4w..4w+3 -> shfl from lane 8k+4*(j>>5).
// ROUND-8 A/B: identical to round 6 except PLAIN stores (NT dropped).
#define KSEG 8

__global__ void __launch_bounds__(256) spike_sigmoid_kernel(
    const float* __restrict__ in, float* __restrict__ out, int nseg) {
  int W = (blockIdx.x * 256 + threadIdx.x) >> 6;  // global wave id
  int lane = threadIdx.x & 63;
  int seg0 = W * KSEG;
  if (seg0 >= nseg) return;
  size_t base = (size_t)seg0 * 64 + lane;
  int sel = lane >> 5;
  int bitpos = 31 - (lane & 31);
  int srcbase = sel * 4;

  if (seg0 + KSEG <= nseg) {
    float f[KSEG];
#pragma unroll
    for (int k = 0; k < KSEG; ++k) f[k] = in[base + (size_t)k * 64];

    unsigned u[16];
#pragma unroll
    for (int k = 0; k < KSEG; ++k) {
      unsigned long long b = __ballot(f[k] > 0.5f);
      u[2 * k]     = __brev((unsigned)b);
      u[2 * k + 1] = __brev((unsigned)(b >> 32));
    }

    // Static select tree: lane L takes value V = L>>2.
    bool p2 = (lane >> 2) & 1, p3 = (lane >> 3) & 1;
    bool p4 = (lane >> 4) & 1, p5 = (lane >> 5) & 1;
    unsigned a0 = p2 ? u[1]  : u[0],  a1 = p2 ? u[3]  : u[2];
    unsigned a2 = p2 ? u[5]  : u[4],  a3 = p2 ? u[7]  : u[6];
    unsigned a4 = p2 ? u[9]  : u[8],  a5 = p2 ? u[11] : u[10];
    unsigned a6 = p2 ? u[13] : u[12], a7 = p2 ? u[15] : u[14];
    unsigned b0 = p3 ? a1 : a0, b1 = p3 ? a3 : a2;
    unsigned b2 = p3 ? a5 : a4, b3 = p3 ? a7 : a6;
    unsigned c0 = p4 ? b1 : b0, c1 = p4 ? b3 : b2;
    unsigned v  = p5 ? c1 : c0;

    float s = xla_sigmoid(__uint_as_float(v));
    unsigned sb = __float_as_uint(s);

#pragma unroll
    for (int k = 0; k < KSEG; ++k) {
      unsigned x = (unsigned)__shfl((int)sb, 8 * k + srcbase);
      out[base + (size_t)k * 64] = (float)((x >> bitpos) & 1u);
    }
  } else {
    // Tail (not taken for nseg=1e6, kept for generality). Wave-uniform trip.
    for (int k = 0; k < KSEG && seg0 + k < nseg; ++k) {
      float fk = in[base + (size_t)k * 64];
      unsigned long long b = __ballot(fk > 0.5f);
      unsigned u0 = __brev((unsigned)b);
      unsigned u1 = __brev((unsigned)(b >> 32));
      unsigned uu = sel ? u1 : u0;
      float s = xla_sigmoid(__uint_as_float(uu));
      unsigned sb = __float_as_uint(s);
      out[base + (size_t)k * 64] = (float)((sb >> bitpos) & 1u);
    }
  }
}

extern "C" void kernel_launch(void* const* d_in, const int* in_sizes, int n_in,
                              void* d_out, int out_size, void* d_ws, size_t ws_size,
                              hipStream_t stream) {
  const float* in = (const float*)d_in[0];
  float* out = (float*)d_out;
  int nseg = in_sizes[0] / 64;                    // 1,000,000 segments (2 values each)
  int waves = (nseg + KSEG - 1) / KSEG;           // 125,000
  long long threads = (long long)waves * 64;      // 8,000,000
  dim3 block(256);
  dim3 grid((unsigned)((threads + 255) / 256));   // 31,250 blocks
  spike_sigmoid_kernel<<<grid, block, 0, stream>>>(in, out, nseg);
}

// Round 9
// 75.195 us; speedup vs baseline: 1.2223x; 1.2223x over previous
//
#include <hip/hip_runtime.h>

// Bit-exact replica of XLA:CPU's vectorized f32 exp AS COMPILED with
// fast-math contraction (== Eigen classic pexp_float with pmadd=FMA on AVX2).
// Non-FMA ops must stay un-contracted -> pragma contract(off) + explicit fmaf.
__device__ __forceinline__ float xla_expf(float xin) {
#pragma clang fp contract(off)
  float xc = fminf(xin, 88.3762626647950f);
  xc = fmaxf(xc, -88.3762626647949f);
  float m = floorf(fmaf(xc, 1.44269504088896341f, 0.5f));
  float r = fmaf(m, -0.693359375f, xc);
  r = fmaf(m, 2.12194440e-4f, r);
  float r2 = r * r;
  float y = 1.9875691500E-4f;            // p0
  y = fmaf(y, r, 1.3981999507E-3f);      // p1
  y = fmaf(y, r, 8.3334519073E-3f);      // p2
  y = fmaf(y, r, 4.1665795894E-2f);      // p3
  y = fmaf(y, r, 1.6666665459E-1f);      // p4
  y = fmaf(y, r, 5.0000001201E-1f);      // p5
  y = fmaf(y, r2, r);
  y = y + 1.0f;
  int n = (int)m;
  float twon = __int_as_float((n + 127) << 23);
  float res = y * twon;
  return fmaxf(res, xin);                // final pmax vs UNCLAMPED input
}

__device__ __forceinline__ float xla_sigmoid(float f) {
#pragma clang fp contract(off)
  float e = xla_expf(-f);
  float denom = 1.0f + e;
  return 1.0f / denom;
}

// Segment = 64 consecutive bit-floats = 2 values. Lane j reads float j of the
// segment (coalesced 4B). ballot(pulse>0.5) -> lo32/hi32 bit-reversed are the
// two value words (wave-uniform). Per 8-segment iteration: 16 uniform values;
// lane L selects value L>>2 via a 15-cndmask static tree and computes ONE
// sigmoid (4x redundancy). Redistribute: lane j / segment k needs value
// 2k+(j>>5), held by lanes 4w..4w+3 -> shfl from lane 8k+4*(j>>5).
// NT stores are ESSENTIAL: A/B'd 75.1 vs 91.9 us — they keep the 256MB output
// stream from evicting the input's L3 residency (FETCH 125MB vs 244MB input).
#define KSEG 8

__global__ void __launch_bounds__(256) spike_sigmoid_kernel(
    const float* __restrict__ in, float* __restrict__ out, int nseg) {
  int W = (blockIdx.x * 256 + threadIdx.x) >> 6;  // global wave id
  int lane = threadIdx.x & 63;
  int seg0 = W * KSEG;
  if (seg0 >= nseg) return;
  size_t base = (size_t)seg0 * 64 + lane;
  int sel = lane >> 5;
  int bitpos = 31 - (lane & 31);
  int srcbase = sel * 4;

  if (seg0 + KSEG <= nseg) {
    float f[KSEG];
#pragma unroll
    for (int k = 0; k < KSEG; ++k) f[k] = in[base + (size_t)k * 64];

    unsigned u[16];
#pragma unroll
    for (int k = 0; k < KSEG; ++k) {
      unsigned long long b = __ballot(f[k] > 0.5f);
      u[2 * k]     = __brev((unsigned)b);
      u[2 * k + 1] = __brev((unsigned)(b >> 32));
    }

    // Static select tree: lane L takes value V = L>>2.
    bool p2 = (lane >> 2) & 1, p3 = (lane >> 3) & 1;
    bool p4 = (lane >> 4) & 1, p5 = (lane >> 5) & 1;
    unsigned a0 = p2 ? u[1]  : u[0],  a1 = p2 ? u[3]  : u[2];
    unsigned a2 = p2 ? u[5]  : u[4],  a3 = p2 ? u[7]  : u[6];
    unsigned a4 = p2 ? u[9]  : u[8],  a5 = p2 ? u[11] : u[10];
    unsigned a6 = p2 ? u[13] : u[12], a7 = p2 ? u[15] : u[14];
    unsigned b0 = p3 ? a1 : a0, b1 = p3 ? a3 : a2;
    unsigned b2 = p3 ? a5 : a4, b3 = p3 ? a7 : a6;
    unsigned c0 = p4 ? b1 : b0, c1 = p4 ? b3 : b2;
    unsigned v  = p5 ? c1 : c0;

    float s = xla_sigmoid(__uint_as_float(v));
    unsigned sb = __float_as_uint(s);

#pragma unroll
    for (int k = 0; k < KSEG; ++k) {
      unsigned x = (unsigned)__shfl((int)sb, 8 * k + srcbase);
      float o = (float)((x >> bitpos) & 1u);
      __builtin_nontemporal_store(o, &out[base + (size_t)k * 64]);
    }
  } else {
    // Tail (not taken for nseg=1e6, kept for generality). Wave-uniform trip.
    for (int k = 0; k < KSEG && seg0 + k < nseg; ++k) {
      float fk = in[base + (size_t)k * 64];
      unsigned long long b = __ballot(fk > 0.5f);
      unsigned u0 = __brev((unsigned)b);
      unsigned u1 = __brev((unsigned)(b >> 32));
      unsigned uu = sel ? u1 : u0;
      float s = xla_sigmoid(__uint_as_float(uu));
      unsigned sb = __float_as_uint(s);
      float o = (float)((sb >> bitpos) & 1u);
      __builtin_nontemporal_store(o, &out[base + (size_t)k * 64]);
    }
  }
}

extern "C" void kernel_launch(void* const* d_in, const int* in_sizes, int n_in,
                              void* d_out, int out_size, void* d_ws, size_t ws_size,
                              hipStream_t stream) {
  const float* in = (const float*)d_in[0];
  float* out = (float*)d_out;
  int nseg = in_sizes[0] / 64;                    // 1,000,000 segments (2 values each)
  int waves = (nseg + KSEG - 1) / KSEG;           // 125,000
  long long threads = (long long)waves * 64;      // 8,000,000
  dim3 block(256);
  dim3 grid((unsigned)((threads + 255) / 256));   // 31,250 blocks
  spike_sigmoid_kernel<<<grid, block, 0, stream>>>(in, out, nseg);
}